// Round 10
// baseline (222.393 us; speedup 1.0000x reference)
//
#include <hip/hip_runtime.h>
#include <math.h>
#include <float.h>

#define CIN 256
#define KCB 4096
#define NPOS 16384  // 16*32*32

// output offsets (in floats)
#define OFF_QUANT 0
#define OFF_IDX   4194304    // 16*256*32*32
#define OFF_LOGIT 4210688    // OFF_IDX + 16*32*32
#define OFF_V     71319552   // OFF_LOGIT + 16*32*32*4096

#define MARGIN 5e-4f  // empirically safe for 1-term bf16 (R7/R8/R9 passed)

typedef short bf16x8 __attribute__((ext_vector_type(8)));
typedef float f32x4 __attribute__((ext_vector_type(4)));

__device__ __forceinline__ unsigned short rne_bf16(float x) {
  const unsigned u = __float_as_uint(x);
  return (unsigned short)((u + 0x7FFFu + ((u >> 16) & 1u)) >> 16);
}

__device__ __forceinline__ void gload_lds16(const void* g, void* l) {
  __builtin_amdgcn_global_load_lds(
      (const __attribute__((address_space(1))) unsigned int*)g,
      (__attribute__((address_space(3))) unsigned int*)l, 16, 0, 0);
}

// merge two top-2 partials over disjoint column sets (min-index tie-break)
__device__ __forceinline__ void top2_merge(float& m1, int& i1, float& m2,
                                           float om1, int oi1, float om2) {
  if (om1 > m1 || (om1 == m1 && oi1 < i1)) {
    m2 = fmaxf(m1, om2);
    m1 = om1;
    i1 = oi1;
  } else {
    m2 = fmaxf(m2, fmaxf(om1, om2));
  }
}

// ---------------------------------------------------------------------------
// K1: fused producers. Blocks [0,256): kmat/v = codebook @ {wk,wv}^T
// (bf16 kb + fp32 kf + fp32 v). Blocks [256,1280): q = latent x wq
// (bf16 qb + fp32 qf; qf lives in the quantized-output region, overwritten
// LAST by gather_kernel). Stays fp32-FMA: refine's exactness needs fp32 q/k.
// ---------------------------------------------------------------------------
__global__ __launch_bounds__(256) void kvq_kernel(
    const float* __restrict__ cb, const float* __restrict__ wk,
    const float* __restrict__ wv, const float* __restrict__ latent,
    const float* __restrict__ wq, unsigned short* __restrict__ kb,
    float* __restrict__ kf, float* __restrict__ vout,
    unsigned short* __restrict__ qb, float* __restrict__ qf) {
  __shared__ float sh[16][CIN];
  const int t = threadIdx.x;
  if (blockIdx.x < 256) {
    // ---- kv path ----
    const int k0 = blockIdx.x * 16;
#pragma unroll
    for (int i = 0; i < 16; ++i)
      sh[i][t] = cb[(size_t)(k0 + i) * CIN + t];
    __syncthreads();
    float acck[16], accv[16];
#pragma unroll
    for (int r = 0; r < 16; ++r) { acck[r] = 0.f; accv[r] = 0.f; }
    const float* wkr = wk + (size_t)t * CIN;
    const float* wvr = wv + (size_t)t * CIN;
    for (int j = 0; j < CIN; ++j) {
      const float a = wkr[j];
      const float b = wvr[j];
#pragma unroll
      for (int r = 0; r < 16; ++r) {
        const float c = sh[r][j];
        acck[r] = fmaf(c, a, acck[r]);
        accv[r] = fmaf(c, b, accv[r]);
      }
    }
#pragma unroll
    for (int r = 0; r < 16; ++r) {
      const float xk = acck[r];
      kb[(size_t)(k0 + r) * CIN + t] = rne_bf16(xk);
      kf[(size_t)(k0 + r) * CIN + t] = xk;
      vout[(size_t)(k0 + r) * CIN + t] = accv[r];
    }
  } else {
    // ---- q path ----
    const int p0 = (blockIdx.x - 256) * 16;
    const int n = p0 >> 10, hw0 = p0 & 1023;
    const float* lbase =
        latent + (size_t)n * (CIN * 1024) + (size_t)t * 1024 + hw0;
#pragma unroll
    for (int i4 = 0; i4 < 4; ++i4) {
      float4 v4 = *(const float4*)(lbase + i4 * 4);
      sh[i4 * 4 + 0][t] = v4.x;
      sh[i4 * 4 + 1][t] = v4.y;
      sh[i4 * 4 + 2][t] = v4.z;
      sh[i4 * 4 + 3][t] = v4.w;
    }
    __syncthreads();
    float acc[16];
#pragma unroll
    for (int r = 0; r < 16; ++r) acc[r] = 0.f;
    const float* wqr = wq + (size_t)t * CIN;
    for (int j = 0; j < CIN; ++j) {
      const float w = wqr[j];
#pragma unroll
      for (int r = 0; r < 16; ++r) acc[r] = fmaf(sh[r][j], w, acc[r]);
    }
#pragma unroll
    for (int r = 0; r < 16; ++r) {
      qb[(size_t)(p0 + r) * CIN + t] = rne_bf16(acc[r]);
      qf[(size_t)(p0 + r) * CIN + t] = acc[r];
    }
  }
}

// ---------------------------------------------------------------------------
// K3: logit = qb kb^T / 16, single-term bf16 MFMA. 128x128 tile, 4 waves,
// BK=32. 3-BUFFER 2-step-ahead prefetch with counted vmcnt(4) (T4 depth-2):
// loads issued at step s land during step s+1's compute and are consumed at
// step s+2 — prefetch stays in flight ACROSS the barrier (the 2-buffer
// vmcnt(0) version serialized every load). 48 KB LDS -> 3 blocks/CU.
// Chunk-XOR LDS swizzle (both-sides involution) on staging/frag reads.
// Logit stores NON-TEMPORAL (write-once stream; keeps qb/kb L2-resident).
// Epilogue: packed top-2 partials via LDS (R7-proven).
// ---------------------------------------------------------------------------
__global__ __launch_bounds__(256, 3) void logit_kernel(
    const unsigned short* __restrict__ qb, const unsigned short* __restrict__ kb,
    float* __restrict__ logit, float* __restrict__ pm1,
    int* __restrict__ pi1, float* __restrict__ pm2) {
  __shared__ __align__(16) unsigned short smem[3][2][128 * 32];  // 48 KB

  const int t = threadIdx.x;
  const int b = blockIdx.x;
  const int x = (b & 7) * 512 + (b >> 3);  // bijective XCD swizzle (4096%8==0)
  const int bn = x & 31, bm = x >> 5;
  const int n0 = bn * 128, m0 = bm * 128;

  const int lane = t & 63, w = t >> 6;
  const int wr = w >> 1, wc = w & 1;
  const int fr = lane & 15, fq = lane >> 4;

  const int srow = t >> 2;                     // staging row within 64-half
  const int spc = t & 3;                       // physical chunk
  const int slog = spc ^ ((srow >> 1) & 3);    // logical (global) chunk
  const int sldse = srow * 32 + spc * 8;       // LDS elem off (t*8: linear)

  // frag read offsets (elements), swizzled
  int aoff[4], boff[4];
#pragma unroll
  for (int mi = 0; mi < 4; ++mi) {
    const int ar = wr * 64 + mi * 16 + fr;
    aoff[mi] = ar * 32 + (fq ^ ((ar >> 1) & 3)) * 8;
  }
#pragma unroll
  for (int ni = 0; ni < 4; ++ni) {
    const int br = wc * 64 + ni * 16 + fr;
    boff[ni] = br * 32 + (fq ^ ((br >> 1) & 3)) * 8;
  }

  f32x4 acc[4][4];
#pragma unroll
  for (int i = 0; i < 4; ++i)
#pragma unroll
    for (int j = 0; j < 4; ++j) acc[i][j] = (f32x4)(0.f);

  // STAGE(dst buffer, k-chunk): 4 gload_lds16 per thread
#define STAGE(DST, K0)                                                       \
  {                                                                          \
    _Pragma("unroll") for (int h = 0; h < 2; ++h) {                          \
      const int r = h * 64 + srow;                                           \
      gload_lds16(qb + (size_t)(m0 + r) * CIN + (K0) + slog * 8,             \
                  &smem[DST][0][h * 2048 + sldse]);                          \
      gload_lds16(kb + (size_t)(n0 + r) * CIN + (K0) + slog * 8,             \
                  &smem[DST][1][h * 2048 + sldse]);                          \
    }                                                                        \
  }

  // prologue: stage steps 0 and 1; wait only for step-0's loads (vmcnt(4))
  STAGE(0, 0)
  STAGE(1, 32)
  asm volatile("s_waitcnt vmcnt(4)" ::: "memory");
  __syncthreads();

#pragma unroll
  for (int s = 0; s < 8; ++s) {
    const int bufc = s % 3;
    if (s < 6) {
      const int nb = (s + 2) % 3;
      STAGE(nb, (s + 2) * 32)
    }
    bf16x8 a[4], bfr[4];
#pragma unroll
    for (int mi = 0; mi < 4; ++mi)
      a[mi] = *(const bf16x8*)&smem[bufc][0][aoff[mi]];
#pragma unroll
    for (int ni = 0; ni < 4; ++ni)
      bfr[ni] = *(const bf16x8*)&smem[bufc][1][boff[ni]];
#pragma unroll
    for (int mi = 0; mi < 4; ++mi)
#pragma unroll
      for (int ni = 0; ni < 4; ++ni)
        acc[mi][ni] = __builtin_amdgcn_mfma_f32_16x16x32_bf16(
            a[mi], bfr[ni], acc[mi][ni], 0, 0, 0);
    // drain loads destined for step s+1; keep this step's issues in flight
    if (s < 6) {
      asm volatile("s_waitcnt vmcnt(4)" ::: "memory");
      __syncthreads();
    } else if (s == 6) {
      asm volatile("s_waitcnt vmcnt(0)" ::: "memory");
      __syncthreads();
    } else {
      __syncthreads();  // protect smem reuse by epilogue
    }
  }
#undef STAGE

  // epilogue: scale, nt-write logit, packed per-lane top2 -> LDS -> partial
  const float sc = 0.0625f;
  float* S1 = (float*)&smem[0][0][0];                 // [2][128][16] 16 KB
  unsigned* S2 = (unsigned*)((char*)&smem[0][0][0] + 16384);  // 16 KB
#pragma unroll
  for (int mi = 0; mi < 4; ++mi)
#pragma unroll
    for (int i = 0; i < 4; ++i) {
      const int rt = wr * 64 + mi * 16 + fq * 4 + i;
      const int row = m0 + rt;
      float vals[4];
#pragma unroll
      for (int ni = 0; ni < 4; ++ni) {
        vals[ni] = acc[mi][ni][i] * sc;
        __builtin_nontemporal_store(
            vals[ni], &logit[(size_t)row * KCB + n0 + wc * 64 + ni * 16 + fr]);
      }
      float m1 = vals[0], m2 = -FLT_MAX;
      int ni1 = 0;
#pragma unroll
      for (int ni = 1; ni < 4; ++ni) {
        if (vals[ni] > m1) { m2 = m1; m1 = vals[ni]; ni1 = ni; }
        else if (vals[ni] > m2) m2 = vals[ni];
      }
      const int sb = (wc * 128 + rt) * 16 + fr;
      S1[sb] = m1;
      S2[sb] = (__float_as_uint(m2) & ~3u) | (unsigned)ni1;
    }
  __syncthreads();
  if (t < 128) {
    float m1 = -FLT_MAX, m2 = -FLT_MAX;
    int i1 = 0;
#pragma unroll
    for (int wc2 = 0; wc2 < 2; ++wc2)
#pragma unroll
      for (int f4 = 0; f4 < 4; ++f4) {
        const int base = (wc2 * 128 + t) * 16 + f4 * 4;
        const float4 am1 = *(const float4*)&S1[base];
        const uint4 au2 = *(const uint4*)&S2[base];
        const unsigned ue[4] = {au2.x, au2.y, au2.z, au2.w};
        const float me[4] = {am1.x, am1.y, am1.z, am1.w};
#pragma unroll
        for (int e = 0; e < 4; ++e) {
          const int col = wc2 * 64 + (int)(ue[e] & 3u) * 16 + f4 * 4 + e;
          top2_merge(m1, i1, m2, me[e], col, __uint_as_float(ue[e] & ~3u));
        }
      }
    pm1[(size_t)(m0 + t) * 32 + bn] = m1;
    pi1[(size_t)(m0 + t) * 32 + bn] = n0 + i1;
    pm2[(size_t)(m0 + t) * 32 + bn] = m2;
  }
}

// ---------------------------------------------------------------------------
// K4a+b fused: merge 32 per-tile top-2 partials per row; flagged rows
// (gap <= MARGIN, includes exact ties) refined IN-BLOCK: one wave per
// flagged row, candidates = logits within MARGIN of row max, exact logit =
// dot(qf,kf)/16 via float4 + shfl. Strict > / min-j = np first-occurrence.
// ---------------------------------------------------------------------------
__global__ __launch_bounds__(256) void easyrefine_kernel(
    const float* __restrict__ pm1, const int* __restrict__ pi1,
    const float* __restrict__ pm2, const float* __restrict__ logit,
    const float* __restrict__ qf, const float* __restrict__ kf,
    int* __restrict__ rowidx_ws) {
  __shared__ float s_rowmax[16];
  __shared__ int s_flag[16];
  __shared__ int s_nflag;
  __shared__ int s_cnt[4];
  __shared__ int s_list[4][64];

  const int t = threadIdx.x;
  const int p0 = blockIdx.x * 16;
  if (t == 0) s_nflag = 0;
  __syncthreads();

  // ---- phase A: merge partials ----
  {
    const int r = t >> 4, l16 = t & 15;
    const int p = p0 + r;
    const size_t base = (size_t)p * 32;
    float m1 = pm1[base + l16], m2 = pm2[base + l16];
    int i1 = pi1[base + l16];
    top2_merge(m1, i1, m2, pm1[base + 16 + l16], pi1[base + 16 + l16],
               pm2[base + 16 + l16]);
#pragma unroll
    for (int mask = 1; mask < 16; mask <<= 1) {
      const float om1 = __shfl_xor(m1, mask, 64);
      const int oi1 = __shfl_xor(i1, mask, 64);
      const float om2 = __shfl_xor(m2, mask, 64);
      top2_merge(m1, i1, m2, om1, oi1, om2);
    }
    if (l16 == 0) {
      rowidx_ws[p] = i1;
      s_rowmax[r] = m1;
      if (m1 - m2 <= MARGIN) {
        const int pos = atomicAdd(&s_nflag, 1);
        s_flag[pos] = r;
      }
    }
  }
  __syncthreads();

  // ---- phase B: in-block refine, one wave per flagged row ----
  const int w = t >> 6, lane = t & 63;
  const int nf = s_nflag;
  for (int fi = w; fi < nf; fi += 4) {
    const int p = p0 + s_flag[fi];
    const float4 qv = *(const float4*)&qf[(size_t)p * CIN + lane * 4];
    if (lane == 0) s_cnt[w] = 0;
    const float thr = s_rowmax[s_flag[fi]] - MARGIN;
    const float* lrow = logit + (size_t)p * KCB;
    for (int it = 0; it < 16; ++it) {
      const float4 xv = *(const float4*)&lrow[lane * 4 + it * 256];
      const float xe[4] = {xv.x, xv.y, xv.z, xv.w};
#pragma unroll
      for (int e = 0; e < 4; ++e) {
        if (xe[e] > thr) {
          const int pos = atomicAdd(&s_cnt[w], 1);
          if (pos < 64) s_list[w][pos] = lane * 4 + it * 256 + e;
        }
      }
    }
    const int nc = min(s_cnt[w], 64);
    float bestv = -FLT_MAX;
    int bestj = 0x7fffffff;
    for (int ci = 0; ci < nc; ++ci) {
      const int j = s_list[w][ci];
      const float4 kv4 = *(const float4*)&kf[(size_t)j * CIN + lane * 4];
      float d = qv.x * kv4.x + qv.y * kv4.y + qv.z * kv4.z + qv.w * kv4.w;
#pragma unroll
      for (int m = 1; m < 64; m <<= 1) d += __shfl_xor(d, m, 64);
      const float val = d * 0.0625f;
      if (val > bestv || (val == bestv && j < bestj)) { bestv = val; bestj = j; }
    }
    if (lane == 0) rowidx_ws[p] = bestj;
  }
}

// ---------------------------------------------------------------------------
// K4c: gather v[idx] -> quantized (soft_v cancels in (hard-soft)+soft to
// ~2ulp), idx as float(idx & 255). Runs LAST: overwrites the qf region.
// ---------------------------------------------------------------------------
__global__ __launch_bounds__(256) void gather_kernel(
    const int* __restrict__ rowidx_ws, const float* __restrict__ vout,
    float* __restrict__ outq, float* __restrict__ outidx) {
  __shared__ int rowidx[16];
  const int t = threadIdx.x;
  const int p0 = blockIdx.x * 16;
  if (t < 16) rowidx[t] = rowidx_ws[p0 + t];
  __syncthreads();
  const int n = p0 >> 10, hw0 = p0 & 1023;
  float res[16];
#pragma unroll
  for (int r2 = 0; r2 < 16; ++r2)
    res[r2] = vout[(size_t)rowidx[r2] * CIN + t];
  float* ob = outq + (size_t)n * (CIN * 1024) + (size_t)t * 1024 + hw0;
#pragma unroll
  for (int i4 = 0; i4 < 4; ++i4)
    *(float4*)&ob[i4 * 4] = make_float4(res[i4 * 4 + 0], res[i4 * 4 + 1],
                                        res[i4 * 4 + 2], res[i4 * 4 + 3]);
  if (t < 16) outidx[p0 + t] = (float)(rowidx[t] & 255);
}

// ---------------------------------------------------------------------------
extern "C" void kernel_launch(void* const* d_in, const int* in_sizes, int n_in,
                              void* d_out, int out_size, void* d_ws,
                              size_t ws_size, hipStream_t stream) {
  const float* latent = (const float*)d_in[0];
  // d_in[1] = temperature (unused in deterministic path)
  const float* codebook = (const float*)d_in[2];
  const float* wq = (const float*)d_in[3];
  const float* wk = (const float*)d_in[4];
  const float* wv = (const float*)d_in[5];

  float* out = (float*)d_out;
  float* outq = out + OFF_QUANT;
  float* outidx = out + OFF_IDX;
  float* outlogit = out + OFF_LOGIT;
  float* outv = out + OFF_V;

  // qf (fp32 q, NPOS*CIN floats) lives in the quantized-output region:
  // easyrefine reads it, gather_kernel overwrites it last.
  float* qf = outq;

  char* ws = (char*)d_ws;
  unsigned short* qb = (unsigned short*)(ws + 0);        // 8 MB
  unsigned short* kb = (unsigned short*)(ws + 8388608);  // 2 MB
  float* kf = (float*)(ws + 10485760);                   // 4 MB
  float* pm1 = (float*)(ws + 14680064);                  // 2 MB
  int* pi1 = (int*)(ws + 16777216);                      // 2 MB
  float* pm2 = (float*)(ws + 18874368);                  // 2 MB
  int* rowidx_ws = (int*)(ws + 20971520);                // 64 KB

  kvq_kernel<<<256 + NPOS / 16, 256, 0, stream>>>(codebook, wk, wv, latent, wq,
                                                  kb, kf, outv, qb, qf);
  logit_kernel<<<4096, 256, 0, stream>>>(qb, kb, outlogit, pm1, pi1, pm2);
  easyrefine_kernel<<<NPOS / 16, 256, 0, stream>>>(pm1, pi1, pm2, outlogit, qf,
                                                   kf, rowidx_ws);
  gather_kernel<<<NPOS / 16, 256, 0, stream>>>(rowidx_ws, outv, outq, outidx);
}

// Round 12
// 217.084 us; speedup vs baseline: 1.0245x; 1.0245x over previous
//
#include <hip/hip_runtime.h>
#include <math.h>
#include <float.h>

#define CIN 256
#define KCB 4096
#define NPOS 16384  // 16*32*32

// output offsets (in floats)
#define OFF_QUANT 0
#define OFF_IDX   4194304    // 16*256*32*32
#define OFF_LOGIT 4210688    // OFF_IDX + 16*32*32
#define OFF_V     71319552   // OFF_LOGIT + 16*32*32*4096

#define MARGIN 5e-4f  // empirically safe for 1-term bf16 (R7/R8/R9/R10 passed)

typedef short bf16x8 __attribute__((ext_vector_type(8)));
typedef float f32x4 __attribute__((ext_vector_type(4)));

__device__ __forceinline__ unsigned short rne_bf16(float x) {
  const unsigned u = __float_as_uint(x);
  return (unsigned short)((u + 0x7FFFu + ((u >> 16) & 1u)) >> 16);
}

__device__ __forceinline__ void gload_lds16(const void* g, void* l) {
  __builtin_amdgcn_global_load_lds(
      (const __attribute__((address_space(1))) unsigned int*)g,
      (__attribute__((address_space(3))) unsigned int*)l, 16, 0, 0);
}

// merge two top-2 partials over disjoint column sets (min-index tie-break)
__device__ __forceinline__ void top2_merge(float& m1, int& i1, float& m2,
                                           float om1, int oi1, float om2) {
  if (om1 > m1 || (om1 == m1 && oi1 < i1)) {
    m2 = fmaxf(m1, om2);
    m1 = om1;
    i1 = oi1;
  } else {
    m2 = fmaxf(m2, fmaxf(om1, om2));
  }
}

// ---------------------------------------------------------------------------
// K1: fused producers. Blocks [0,256): kmat/v = codebook @ {wk,wv}^T
// (bf16 kb + fp32 kf + fp32 v). Blocks [256,1280): q = latent x wq
// (bf16 qb + fp32 qf; qf lives in the quantized-output region, overwritten
// LAST by gather_kernel). Stays fp32-FMA: refine's exactness needs fp32 q/k.
// ---------------------------------------------------------------------------
__global__ __launch_bounds__(256) void kvq_kernel(
    const float* __restrict__ cb, const float* __restrict__ wk,
    const float* __restrict__ wv, const float* __restrict__ latent,
    const float* __restrict__ wq, unsigned short* __restrict__ kb,
    float* __restrict__ kf, float* __restrict__ vout,
    unsigned short* __restrict__ qb, float* __restrict__ qf) {
  __shared__ float sh[16][CIN];
  const int t = threadIdx.x;
  if (blockIdx.x < 256) {
    // ---- kv path ----
    const int k0 = blockIdx.x * 16;
#pragma unroll
    for (int i = 0; i < 16; ++i)
      sh[i][t] = cb[(size_t)(k0 + i) * CIN + t];
    __syncthreads();
    float acck[16], accv[16];
#pragma unroll
    for (int r = 0; r < 16; ++r) { acck[r] = 0.f; accv[r] = 0.f; }
    const float* wkr = wk + (size_t)t * CIN;
    const float* wvr = wv + (size_t)t * CIN;
    for (int j = 0; j < CIN; ++j) {
      const float a = wkr[j];
      const float b = wvr[j];
#pragma unroll
      for (int r = 0; r < 16; ++r) {
        const float c = sh[r][j];
        acck[r] = fmaf(c, a, acck[r]);
        accv[r] = fmaf(c, b, accv[r]);
      }
    }
#pragma unroll
    for (int r = 0; r < 16; ++r) {
      const float xk = acck[r];
      kb[(size_t)(k0 + r) * CIN + t] = rne_bf16(xk);
      kf[(size_t)(k0 + r) * CIN + t] = xk;
      vout[(size_t)(k0 + r) * CIN + t] = accv[r];
    }
  } else {
    // ---- q path ----
    const int p0 = (blockIdx.x - 256) * 16;
    const int n = p0 >> 10, hw0 = p0 & 1023;
    const float* lbase =
        latent + (size_t)n * (CIN * 1024) + (size_t)t * 1024 + hw0;
#pragma unroll
    for (int i4 = 0; i4 < 4; ++i4) {
      float4 v4 = *(const float4*)(lbase + i4 * 4);
      sh[i4 * 4 + 0][t] = v4.x;
      sh[i4 * 4 + 1][t] = v4.y;
      sh[i4 * 4 + 2][t] = v4.z;
      sh[i4 * 4 + 3][t] = v4.w;
    }
    __syncthreads();
    float acc[16];
#pragma unroll
    for (int r = 0; r < 16; ++r) acc[r] = 0.f;
    const float* wqr = wq + (size_t)t * CIN;
    for (int j = 0; j < CIN; ++j) {
      const float w = wqr[j];
#pragma unroll
      for (int r = 0; r < 16; ++r) acc[r] = fmaf(sh[r][j], w, acc[r]);
    }
#pragma unroll
    for (int r = 0; r < 16; ++r) {
      qb[(size_t)(p0 + r) * CIN + t] = rne_bf16(acc[r]);
      qf[(size_t)(p0 + r) * CIN + t] = acc[r];
    }
  }
}

// ---------------------------------------------------------------------------
// K3: logit = qb kb^T / 16, single-term bf16 MFMA. 128x128 tile, 4 waves,
// BK=32, double-buffered global_load_lds (R9-proven loop; 32 KB LDS ->
// 4 blocks/CU). Chunk-XOR LDS swizzle on staging/frag reads.
// Epilogue phase 1: per-wave LDS transpose (16x66 pad, wave-local lgkmcnt
// fences only — no cross-wave coupling) -> nt f32x4 stores, 256B-contiguous
// per 16 lanes (HBM row locality; scalar 64B-scattered stores drained at
// ~1.7 TB/s). Phase 2: packed top-2 partials via LDS (R9-proven).
// ---------------------------------------------------------------------------
__global__ __launch_bounds__(256, 4) void logit_kernel(
    const unsigned short* __restrict__ qb, const unsigned short* __restrict__ kb,
    float* __restrict__ logit, float* __restrict__ pm1,
    int* __restrict__ pi1, float* __restrict__ pm2) {
  __shared__ __align__(16) unsigned short smem[2][2][128 * 32];  // 32 KB

  const int t = threadIdx.x;
  const int b = blockIdx.x;
  const int x = (b & 7) * 512 + (b >> 3);  // bijective XCD swizzle (4096%8==0)
  const int bn = x & 31, bm = x >> 5;
  const int n0 = bn * 128, m0 = bm * 128;

  const int lane = t & 63, w = t >> 6;
  const int wr = w >> 1, wc = w & 1;
  const int fr = lane & 15, fq = lane >> 4;

  const int srow = t >> 2;                     // staging row within 64-half
  const int spc = t & 3;                       // physical chunk
  const int slog = spc ^ ((srow >> 1) & 3);    // logical (global) chunk
  const int sldse = srow * 32 + spc * 8;       // LDS elem off (t*8: linear)

  // frag read offsets (elements), swizzled
  int aoff[4], boff[4];
#pragma unroll
  for (int mi = 0; mi < 4; ++mi) {
    const int ar = wr * 64 + mi * 16 + fr;
    aoff[mi] = ar * 32 + (fq ^ ((ar >> 1) & 3)) * 8;
  }
#pragma unroll
  for (int ni = 0; ni < 4; ++ni) {
    const int br = wc * 64 + ni * 16 + fr;
    boff[ni] = br * 32 + (fq ^ ((br >> 1) & 3)) * 8;
  }

  f32x4 acc[4][4];
#pragma unroll
  for (int i = 0; i < 4; ++i)
#pragma unroll
    for (int j = 0; j < 4; ++j) acc[i][j] = (f32x4)(0.f);

  // prologue: stage step 0 into buf 0
#pragma unroll
  for (int h = 0; h < 2; ++h) {
    const int r = h * 64 + srow;
    gload_lds16(qb + (size_t)(m0 + r) * CIN + slog * 8,
                &smem[0][0][h * 2048 + sldse]);
    gload_lds16(kb + (size_t)(n0 + r) * CIN + slog * 8,
                &smem[0][1][h * 2048 + sldse]);
  }
  asm volatile("s_waitcnt vmcnt(0)" ::: "memory");
  __syncthreads();

  for (int s = 0; s < 8; ++s) {
    const int buf = s & 1;
    if (s < 7) {  // stage next tile into the other buffer
      const int k0 = (s + 1) * 32;
      const int nb = buf ^ 1;
#pragma unroll
      for (int h = 0; h < 2; ++h) {
        const int r = h * 64 + srow;
        gload_lds16(qb + (size_t)(m0 + r) * CIN + k0 + slog * 8,
                    &smem[nb][0][h * 2048 + sldse]);
        gload_lds16(kb + (size_t)(n0 + r) * CIN + k0 + slog * 8,
                    &smem[nb][1][h * 2048 + sldse]);
      }
    }
    bf16x8 a[4], bfr[4];
#pragma unroll
    for (int mi = 0; mi < 4; ++mi) a[mi] = *(const bf16x8*)&smem[buf][0][aoff[mi]];
#pragma unroll
    for (int ni = 0; ni < 4; ++ni) bfr[ni] = *(const bf16x8*)&smem[buf][1][boff[ni]];
#pragma unroll
    for (int mi = 0; mi < 4; ++mi)
#pragma unroll
      for (int ni = 0; ni < 4; ++ni)
        acc[mi][ni] = __builtin_amdgcn_mfma_f32_16x16x32_bf16(
            a[mi], bfr[ni], acc[mi][ni], 0, 0, 0);
    asm volatile("s_waitcnt vmcnt(0)" ::: "memory");
    __syncthreads();
  }

  const float sc = 0.0625f;

  // ---- epilogue phase 1: wave-private transpose -> coalesced nt stores ----
  {
    float* tb = (float*)&smem[0][0][0] + (size_t)w * 1056;  // [16][66] floats
    const int row16r = (lane >> 4);  // base row for read-back
    const int c4 = lane & 15;
#pragma unroll
    for (int mi = 0; mi < 4; ++mi) {
#pragma unroll
      for (int ni = 0; ni < 4; ++ni)
#pragma unroll
        for (int i = 0; i < 4; ++i)
          tb[(fq * 4 + i) * 66 + ni * 16 + fr] = acc[mi][ni][i] * sc;
      asm volatile("s_waitcnt lgkmcnt(0)" ::: "memory");
      __builtin_amdgcn_sched_barrier(0);
#pragma unroll
      for (int j = 0; j < 4; ++j) {
        const int rl = row16r + j * 4;
        const f32x4 vv = *(const f32x4*)&tb[rl * 66 + c4 * 4];
        __builtin_nontemporal_store(
            vv, (f32x4*)&logit[(size_t)(m0 + wr * 64 + mi * 16 + rl) * KCB +
                               n0 + wc * 64 + c4 * 4]);
      }
      asm volatile("s_waitcnt lgkmcnt(0)" ::: "memory");
      __builtin_amdgcn_sched_barrier(0);
    }
  }
  __syncthreads();

  // ---- epilogue phase 2: packed per-lane top2 -> LDS -> tile partial ----
  float* S1 = (float*)&smem[0][0][0];                 // [2][128][16] 16 KB
  unsigned* S2 = (unsigned*)((char*)&smem[0][0][0] + 16384);  // 16 KB
#pragma unroll
  for (int mi = 0; mi < 4; ++mi)
#pragma unroll
    for (int i = 0; i < 4; ++i) {
      const int rt = wr * 64 + mi * 16 + fq * 4 + i;
      float vals[4];
#pragma unroll
      for (int ni = 0; ni < 4; ++ni) vals[ni] = acc[mi][ni][i] * sc;
      float m1 = vals[0], m2 = -FLT_MAX;
      int ni1 = 0;
#pragma unroll
      for (int ni = 1; ni < 4; ++ni) {
        if (vals[ni] > m1) { m2 = m1; m1 = vals[ni]; ni1 = ni; }
        else if (vals[ni] > m2) m2 = vals[ni];
      }
      const int sb = (wc * 128 + rt) * 16 + fr;
      S1[sb] = m1;
      S2[sb] = (__float_as_uint(m2) & ~3u) | (unsigned)ni1;
    }
  __syncthreads();
  if (t < 128) {
    float m1 = -FLT_MAX, m2 = -FLT_MAX;
    int i1 = 0;
#pragma unroll
    for (int wc2 = 0; wc2 < 2; ++wc2)
#pragma unroll
      for (int f4 = 0; f4 < 4; ++f4) {
        const int base = (wc2 * 128 + t) * 16 + f4 * 4;
        const float4 am1 = *(const float4*)&S1[base];
        const uint4 au2 = *(const uint4*)&S2[base];
        const unsigned ue[4] = {au2.x, au2.y, au2.z, au2.w};
        const float me[4] = {am1.x, am1.y, am1.z, am1.w};
#pragma unroll
        for (int e = 0; e < 4; ++e) {
          const int col = wc2 * 64 + (int)(ue[e] & 3u) * 16 + f4 * 4 + e;
          top2_merge(m1, i1, m2, me[e], col, __uint_as_float(ue[e] & ~3u));
        }
      }
    pm1[(size_t)(m0 + t) * 32 + bn] = m1;
    pi1[(size_t)(m0 + t) * 32 + bn] = n0 + i1;
    pm2[(size_t)(m0 + t) * 32 + bn] = m2;
  }
}

// ---------------------------------------------------------------------------
// K4a+b fused: merge 32 per-tile top-2 partials per row; flagged rows
// (gap <= MARGIN, includes exact ties) refined IN-BLOCK: one wave per
// flagged row, candidates = logits within MARGIN of row max, exact logit =
// dot(qf,kf)/16 via float4 + shfl. Strict > / min-j = np first-occurrence.
// ---------------------------------------------------------------------------
__global__ __launch_bounds__(256) void easyrefine_kernel(
    const float* __restrict__ pm1, const int* __restrict__ pi1,
    const float* __restrict__ pm2, const float* __restrict__ logit,
    const float* __restrict__ qf, const float* __restrict__ kf,
    int* __restrict__ rowidx_ws) {
  __shared__ float s_rowmax[16];
  __shared__ int s_flag[16];
  __shared__ int s_nflag;
  __shared__ int s_cnt[4];
  __shared__ int s_list[4][64];

  const int t = threadIdx.x;
  const int p0 = blockIdx.x * 16;
  if (t == 0) s_nflag = 0;
  __syncthreads();

  // ---- phase A: merge partials ----
  {
    const int r = t >> 4, l16 = t & 15;
    const int p = p0 + r;
    const size_t base = (size_t)p * 32;
    float m1 = pm1[base + l16], m2 = pm2[base + l16];
    int i1 = pi1[base + l16];
    top2_merge(m1, i1, m2, pm1[base + 16 + l16], pi1[base + 16 + l16],
               pm2[base + 16 + l16]);
#pragma unroll
    for (int mask = 1; mask < 16; mask <<= 1) {
      const float om1 = __shfl_xor(m1, mask, 64);
      const int oi1 = __shfl_xor(i1, mask, 64);
      const float om2 = __shfl_xor(m2, mask, 64);
      top2_merge(m1, i1, m2, om1, oi1, om2);
    }
    if (l16 == 0) {
      rowidx_ws[p] = i1;
      s_rowmax[r] = m1;
      if (m1 - m2 <= MARGIN) {
        const int pos = atomicAdd(&s_nflag, 1);
        s_flag[pos] = r;
      }
    }
  }
  __syncthreads();

  // ---- phase B: in-block refine, one wave per flagged row ----
  const int w = t >> 6, lane = t & 63;
  const int nf = s_nflag;
  for (int fi = w; fi < nf; fi += 4) {
    const int p = p0 + s_flag[fi];
    const float4 qv = *(const float4*)&qf[(size_t)p * CIN + lane * 4];
    if (lane == 0) s_cnt[w] = 0;
    const float thr = s_rowmax[s_flag[fi]] - MARGIN;
    const float* lrow = logit + (size_t)p * KCB;
    for (int it = 0; it < 16; ++it) {
      const float4 xv = *(const float4*)&lrow[lane * 4 + it * 256];
      const float xe[4] = {xv.x, xv.y, xv.z, xv.w};
#pragma unroll
      for (int e = 0; e < 4; ++e) {
        if (xe[e] > thr) {
          const int pos = atomicAdd(&s_cnt[w], 1);
          if (pos < 64) s_list[w][pos] = lane * 4 + it * 256 + e;
        }
      }
    }
    const int nc = min(s_cnt[w], 64);
    float bestv = -FLT_MAX;
    int bestj = 0x7fffffff;
    for (int ci = 0; ci < nc; ++ci) {
      const int j = s_list[w][ci];
      const float4 kv4 = *(const float4*)&kf[(size_t)j * CIN + lane * 4];
      float d = qv.x * kv4.x + qv.y * kv4.y + qv.z * kv4.z + qv.w * kv4.w;
#pragma unroll
      for (int m = 1; m < 64; m <<= 1) d += __shfl_xor(d, m, 64);
      const float val = d * 0.0625f;
      if (val > bestv || (val == bestv && j < bestj)) { bestv = val; bestj = j; }
    }
    if (lane == 0) rowidx_ws[p] = bestj;
  }
}

// ---------------------------------------------------------------------------
// K4c: gather v[idx] -> quantized (soft_v cancels in (hard-soft)+soft to
// ~2ulp), idx as float(idx & 255). Runs LAST: overwrites the qf region.
// ---------------------------------------------------------------------------
__global__ __launch_bounds__(256) void gather_kernel(
    const int* __restrict__ rowidx_ws, const float* __restrict__ vout,
    float* __restrict__ outq, float* __restrict__ outidx) {
  __shared__ int rowidx[16];
  const int t = threadIdx.x;
  const int p0 = blockIdx.x * 16;
  if (t < 16) rowidx[t] = rowidx_ws[p0 + t];
  __syncthreads();
  const int n = p0 >> 10, hw0 = p0 & 1023;
  float res[16];
#pragma unroll
  for (int r2 = 0; r2 < 16; ++r2)
    res[r2] = vout[(size_t)rowidx[r2] * CIN + t];
  float* ob = outq + (size_t)n * (CIN * 1024) + (size_t)t * 1024 + hw0;
#pragma unroll
  for (int i4 = 0; i4 < 4; ++i4)
    *(float4*)&ob[i4 * 4] = make_float4(res[i4 * 4 + 0], res[i4 * 4 + 1],
                                        res[i4 * 4 + 2], res[i4 * 4 + 3]);
  if (t < 16) outidx[p0 + t] = (float)(rowidx[t] & 255);
}

// ---------------------------------------------------------------------------
extern "C" void kernel_launch(void* const* d_in, const int* in_sizes, int n_in,
                              void* d_out, int out_size, void* d_ws,
                              size_t ws_size, hipStream_t stream) {
  const float* latent = (const float*)d_in[0];
  // d_in[1] = temperature (unused in deterministic path)
  const float* codebook = (const float*)d_in[2];
  const float* wq = (const float*)d_in[3];
  const float* wk = (const float*)d_in[4];
  const float* wv = (const float*)d_in[5];

  float* out = (float*)d_out;
  float* outq = out + OFF_QUANT;
  float* outidx = out + OFF_IDX;
  float* outlogit = out + OFF_LOGIT;
  float* outv = out + OFF_V;

  // qf (fp32 q, NPOS*CIN floats) lives in the quantized-output region:
  // easyrefine reads it, gather_kernel overwrites it last.
  float* qf = outq;

  char* ws = (char*)d_ws;
  unsigned short* qb = (unsigned short*)(ws + 0);        // 8 MB
  unsigned short* kb = (unsigned short*)(ws + 8388608);  // 2 MB
  float* kf = (float*)(ws + 10485760);                   // 4 MB
  float* pm1 = (float*)(ws + 14680064);                  // 2 MB
  int* pi1 = (int*)(ws + 16777216);                      // 2 MB
  float* pm2 = (float*)(ws + 18874368);                  // 2 MB
  int* rowidx_ws = (int*)(ws + 20971520);                // 64 KB

  kvq_kernel<<<256 + NPOS / 16, 256, 0, stream>>>(codebook, wk, wv, latent, wq,
                                                  kb, kf, outv, qb, qf);
  logit_kernel<<<4096, 256, 0, stream>>>(qb, kb, outlogit, pm1, pi1, pm2);
  easyrefine_kernel<<<NPOS / 16, 256, 0, stream>>>(pm1, pi1, pm2, outlogit, qf,
                                                   kf, rowidx_ws);
  gather_kernel<<<NPOS / 16, 256, 0, stream>>>(rowidx_ws, outv, outq, outidx);
}

// Round 13
// 166.864 us; speedup vs baseline: 1.3328x; 1.3010x over previous
//
#include <hip/hip_runtime.h>
#include <math.h>
#include <float.h>

#define CIN 256
#define KCB 4096
#define NPOS 16384  // 16*32*32

// output offsets (in floats)
#define OFF_QUANT 0
#define OFF_IDX   4194304    // 16*256*32*32
#define OFF_LOGIT 4210688    // OFF_IDX + 16*32*32
#define OFF_V     71319552   // OFF_LOGIT + 16*32*32*4096

#define MARGIN 5e-4f  // empirically safe for 1-term bf16 (R7-R12 passed)

typedef short bf16x8 __attribute__((ext_vector_type(8)));
typedef float f32x4 __attribute__((ext_vector_type(4)));

__device__ __forceinline__ unsigned short rne_bf16(float x) {
  const unsigned u = __float_as_uint(x);
  return (unsigned short)((u + 0x7FFFu + ((u >> 16) & 1u)) >> 16);
}

__device__ __forceinline__ void gload_lds16(const void* g, void* l) {
  __builtin_amdgcn_global_load_lds(
      (const __attribute__((address_space(1))) unsigned int*)g,
      (__attribute__((address_space(3))) unsigned int*)l, 16, 0, 0);
}

// merge two top-2 partials over disjoint column sets (min-index tie-break)
__device__ __forceinline__ void top2_merge(float& m1, int& i1, float& m2,
                                           float om1, int oi1, float om2) {
  if (om1 > m1 || (om1 == m1 && oi1 < i1)) {
    m2 = fmaxf(m1, om2);
    m1 = om1;
    i1 = oi1;
  } else {
    m2 = fmaxf(m2, fmaxf(om1, om2));
  }
}

// ---------------------------------------------------------------------------
// K1: fused producers. Blocks [0,256): kmat/v = codebook @ {wk,wv}^T
// (bf16 kb + fp32 kf + fp32 v). Blocks [256,1280): q = latent x wq
// (bf16 qb + fp32 qf, both in ws). fp32-FMA with float4 weight loads —
// identical fmaf sequence (bit-identical outputs), 4x fewer scattered loads.
// ---------------------------------------------------------------------------
__global__ __launch_bounds__(256) void kvq_kernel(
    const float* __restrict__ cb, const float* __restrict__ wk,
    const float* __restrict__ wv, const float* __restrict__ latent,
    const float* __restrict__ wq, unsigned short* __restrict__ kb,
    float* __restrict__ kf, float* __restrict__ vout,
    unsigned short* __restrict__ qb, float* __restrict__ qf) {
  __shared__ float sh[16][CIN];
  const int t = threadIdx.x;
  if (blockIdx.x < 256) {
    // ---- kv path ----
    const int k0 = blockIdx.x * 16;
#pragma unroll
    for (int i = 0; i < 16; ++i)
      sh[i][t] = cb[(size_t)(k0 + i) * CIN + t];
    __syncthreads();
    float acck[16], accv[16];
#pragma unroll
    for (int r = 0; r < 16; ++r) { acck[r] = 0.f; accv[r] = 0.f; }
    const float* wkr = wk + (size_t)t * CIN;
    const float* wvr = wv + (size_t)t * CIN;
    for (int j4 = 0; j4 < CIN; j4 += 4) {
      const float4 a4 = *(const float4*)&wkr[j4];
      const float4 b4 = *(const float4*)&wvr[j4];
      const float ae[4] = {a4.x, a4.y, a4.z, a4.w};
      const float be[4] = {b4.x, b4.y, b4.z, b4.w};
#pragma unroll
      for (int e = 0; e < 4; ++e) {
        const int j = j4 + e;
#pragma unroll
        for (int r = 0; r < 16; ++r) {
          const float c = sh[r][j];
          acck[r] = fmaf(c, ae[e], acck[r]);
          accv[r] = fmaf(c, be[e], accv[r]);
        }
      }
    }
#pragma unroll
    for (int r = 0; r < 16; ++r) {
      const float xk = acck[r];
      kb[(size_t)(k0 + r) * CIN + t] = rne_bf16(xk);
      kf[(size_t)(k0 + r) * CIN + t] = xk;
      vout[(size_t)(k0 + r) * CIN + t] = accv[r];
    }
  } else {
    // ---- q path ----
    const int p0 = (blockIdx.x - 256) * 16;
    const int n = p0 >> 10, hw0 = p0 & 1023;
    const float* lbase =
        latent + (size_t)n * (CIN * 1024) + (size_t)t * 1024 + hw0;
#pragma unroll
    for (int i4 = 0; i4 < 4; ++i4) {
      float4 v4 = *(const float4*)(lbase + i4 * 4);
      sh[i4 * 4 + 0][t] = v4.x;
      sh[i4 * 4 + 1][t] = v4.y;
      sh[i4 * 4 + 2][t] = v4.z;
      sh[i4 * 4 + 3][t] = v4.w;
    }
    __syncthreads();
    float acc[16];
#pragma unroll
    for (int r = 0; r < 16; ++r) acc[r] = 0.f;
    const float* wqr = wq + (size_t)t * CIN;
    for (int j4 = 0; j4 < CIN; j4 += 4) {
      const float4 w4 = *(const float4*)&wqr[j4];
      const float we[4] = {w4.x, w4.y, w4.z, w4.w};
#pragma unroll
      for (int e = 0; e < 4; ++e) {
        const int j = j4 + e;
#pragma unroll
        for (int r = 0; r < 16; ++r) acc[r] = fmaf(sh[r][j], we[e], acc[r]);
      }
    }
#pragma unroll
    for (int r = 0; r < 16; ++r) {
      qb[(size_t)(p0 + r) * CIN + t] = rne_bf16(acc[r]);
      qf[(size_t)(p0 + r) * CIN + t] = acc[r];
    }
  }
}

// ---------------------------------------------------------------------------
// K3: logit = qb kb^T / 16, single-term bf16 MFMA. 128x128 tile, 4 waves,
// BK=32, double-buffered global_load_lds (R9-proven; 32 KB LDS ->
// 4 blocks/CU). Chunk-XOR LDS swizzle on staging/frag reads.
// Logit stores NON-TEMPORAL (write-once stream; keeps qb/kb L2-resident).
// Epilogue: packed top-2 partials via LDS (R9-proven).
// ---------------------------------------------------------------------------
__global__ __launch_bounds__(256, 4) void logit_kernel(
    const unsigned short* __restrict__ qb, const unsigned short* __restrict__ kb,
    float* __restrict__ logit, float* __restrict__ pm1,
    int* __restrict__ pi1, float* __restrict__ pm2) {
  __shared__ __align__(16) unsigned short smem[2][2][128 * 32];  // 32 KB

  const int t = threadIdx.x;
  const int b = blockIdx.x;
  const int x = (b & 7) * 512 + (b >> 3);  // bijective XCD swizzle (4096%8==0)
  const int bn = x & 31, bm = x >> 5;
  const int n0 = bn * 128, m0 = bm * 128;

  const int lane = t & 63, w = t >> 6;
  const int wr = w >> 1, wc = w & 1;
  const int fr = lane & 15, fq = lane >> 4;

  const int srow = t >> 2;                     // staging row within 64-half
  const int spc = t & 3;                       // physical chunk
  const int slog = spc ^ ((srow >> 1) & 3);    // logical (global) chunk
  const int sldse = srow * 32 + spc * 8;       // LDS elem off (t*8: linear)

  // frag read offsets (elements), swizzled
  int aoff[4], boff[4];
#pragma unroll
  for (int mi = 0; mi < 4; ++mi) {
    const int ar = wr * 64 + mi * 16 + fr;
    aoff[mi] = ar * 32 + (fq ^ ((ar >> 1) & 3)) * 8;
  }
#pragma unroll
  for (int ni = 0; ni < 4; ++ni) {
    const int br = wc * 64 + ni * 16 + fr;
    boff[ni] = br * 32 + (fq ^ ((br >> 1) & 3)) * 8;
  }

  f32x4 acc[4][4];
#pragma unroll
  for (int i = 0; i < 4; ++i)
#pragma unroll
    for (int j = 0; j < 4; ++j) acc[i][j] = (f32x4)(0.f);

  // prologue: stage step 0 into buf 0
#pragma unroll
  for (int h = 0; h < 2; ++h) {
    const int r = h * 64 + srow;
    gload_lds16(qb + (size_t)(m0 + r) * CIN + slog * 8,
                &smem[0][0][h * 2048 + sldse]);
    gload_lds16(kb + (size_t)(n0 + r) * CIN + slog * 8,
                &smem[0][1][h * 2048 + sldse]);
  }
  asm volatile("s_waitcnt vmcnt(0)" ::: "memory");
  __syncthreads();

  for (int s = 0; s < 8; ++s) {
    const int buf = s & 1;
    if (s < 7) {  // stage next tile into the other buffer
      const int k0 = (s + 1) * 32;
      const int nb = buf ^ 1;
#pragma unroll
      for (int h = 0; h < 2; ++h) {
        const int r = h * 64 + srow;
        gload_lds16(qb + (size_t)(m0 + r) * CIN + k0 + slog * 8,
                    &smem[nb][0][h * 2048 + sldse]);
        gload_lds16(kb + (size_t)(n0 + r) * CIN + k0 + slog * 8,
                    &smem[nb][1][h * 2048 + sldse]);
      }
    }
    bf16x8 a[4], bfr[4];
#pragma unroll
    for (int mi = 0; mi < 4; ++mi) a[mi] = *(const bf16x8*)&smem[buf][0][aoff[mi]];
#pragma unroll
    for (int ni = 0; ni < 4; ++ni) bfr[ni] = *(const bf16x8*)&smem[buf][1][boff[ni]];
#pragma unroll
    for (int mi = 0; mi < 4; ++mi)
#pragma unroll
      for (int ni = 0; ni < 4; ++ni)
        acc[mi][ni] = __builtin_amdgcn_mfma_f32_16x16x32_bf16(
            a[mi], bfr[ni], acc[mi][ni], 0, 0, 0);
    asm volatile("s_waitcnt vmcnt(0)" ::: "memory");
    __syncthreads();
  }

  // epilogue: scale, nt-write logit, packed per-lane top2 -> LDS -> partial
  const float sc = 0.0625f;
  float* S1 = (float*)&smem[0][0][0];                 // [2][128][16] 16 KB
  unsigned* S2 = (unsigned*)((char*)&smem[0][0][0] + 16384);  // 16 KB
#pragma unroll
  for (int mi = 0; mi < 4; ++mi)
#pragma unroll
    for (int i = 0; i < 4; ++i) {
      const int rt = wr * 64 + mi * 16 + fq * 4 + i;
      const int row = m0 + rt;
      float vals[4];
#pragma unroll
      for (int ni = 0; ni < 4; ++ni) {
        vals[ni] = acc[mi][ni][i] * sc;
        __builtin_nontemporal_store(
            vals[ni], &logit[(size_t)row * KCB + n0 + wc * 64 + ni * 16 + fr]);
      }
      float m1 = vals[0], m2 = -FLT_MAX;
      int ni1 = 0;
#pragma unroll
      for (int ni = 1; ni < 4; ++ni) {
        if (vals[ni] > m1) { m2 = m1; m1 = vals[ni]; ni1 = ni; }
        else if (vals[ni] > m2) m2 = vals[ni];
      }
      const int sb = (wc * 128 + rt) * 16 + fr;
      S1[sb] = m1;
      S2[sb] = (__float_as_uint(m2) & ~3u) | (unsigned)ni1;
    }
  __syncthreads();
  if (t < 128) {
    float m1 = -FLT_MAX, m2 = -FLT_MAX;
    int i1 = 0;
#pragma unroll
    for (int wc2 = 0; wc2 < 2; ++wc2)
#pragma unroll
      for (int f4 = 0; f4 < 4; ++f4) {
        const int base = (wc2 * 128 + t) * 16 + f4 * 4;
        const float4 am1 = *(const float4*)&S1[base];
        const uint4 au2 = *(const uint4*)&S2[base];
        const unsigned ue[4] = {au2.x, au2.y, au2.z, au2.w};
        const float me[4] = {am1.x, am1.y, am1.z, am1.w};
#pragma unroll
        for (int e = 0; e < 4; ++e) {
          const int col = wc2 * 64 + (int)(ue[e] & 3u) * 16 + f4 * 4 + e;
          top2_merge(m1, i1, m2, me[e], col, __uint_as_float(ue[e] & ~3u));
        }
      }
    pm1[(size_t)(m0 + t) * 32 + bn] = m1;
    pi1[(size_t)(m0 + t) * 32 + bn] = n0 + i1;
    pm2[(size_t)(m0 + t) * 32 + bn] = m2;
  }
}

// ---------------------------------------------------------------------------
// K4 (fully fused finish): phase A merges 32 per-tile top-2 partials per row;
// phase B refines flagged rows (gap <= MARGIN, incl. exact ties) in-block
// with exact fp32 dots (np.argmax first-occurrence); phase C gathers v[idx]
// -> quantized ((hard-soft)+soft == hard to ~2ulp) + idx floats. rowidx
// never leaves LDS.
// ---------------------------------------------------------------------------
__global__ __launch_bounds__(256) void finish_kernel(
    const float* __restrict__ pm1, const int* __restrict__ pi1,
    const float* __restrict__ pm2, const float* __restrict__ logit,
    const float* __restrict__ qf, const float* __restrict__ kf,
    const float* __restrict__ vout, float* __restrict__ outq,
    float* __restrict__ outidx) {
  __shared__ float s_rowmax[16];
  __shared__ int s_rowidx[16];
  __shared__ int s_flag[16];
  __shared__ int s_nflag;
  __shared__ int s_cnt[4];
  __shared__ int s_list[4][64];

  const int t = threadIdx.x;
  const int p0 = blockIdx.x * 16;
  if (t == 0) s_nflag = 0;
  __syncthreads();

  // ---- phase A: merge partials ----
  {
    const int r = t >> 4, l16 = t & 15;
    const int p = p0 + r;
    const size_t base = (size_t)p * 32;
    float m1 = pm1[base + l16], m2 = pm2[base + l16];
    int i1 = pi1[base + l16];
    top2_merge(m1, i1, m2, pm1[base + 16 + l16], pi1[base + 16 + l16],
               pm2[base + 16 + l16]);
#pragma unroll
    for (int mask = 1; mask < 16; mask <<= 1) {
      const float om1 = __shfl_xor(m1, mask, 64);
      const int oi1 = __shfl_xor(i1, mask, 64);
      const float om2 = __shfl_xor(m2, mask, 64);
      top2_merge(m1, i1, m2, om1, oi1, om2);
    }
    if (l16 == 0) {
      s_rowidx[r] = i1;
      s_rowmax[r] = m1;
      if (m1 - m2 <= MARGIN) {
        const int pos = atomicAdd(&s_nflag, 1);
        s_flag[pos] = r;
      }
    }
  }
  __syncthreads();

  // ---- phase B: in-block refine, one wave per flagged row ----
  const int w = t >> 6, lane = t & 63;
  const int nf = s_nflag;
  for (int fi = w; fi < nf; fi += 4) {
    const int rloc = s_flag[fi];
    const int p = p0 + rloc;
    const float4 qv = *(const float4*)&qf[(size_t)p * CIN + lane * 4];
    if (lane == 0) s_cnt[w] = 0;
    const float thr = s_rowmax[rloc] - MARGIN;
    const float* lrow = logit + (size_t)p * KCB;
    for (int it = 0; it < 16; ++it) {
      const float4 xv = *(const float4*)&lrow[lane * 4 + it * 256];
      const float xe[4] = {xv.x, xv.y, xv.z, xv.w};
#pragma unroll
      for (int e = 0; e < 4; ++e) {
        if (xe[e] > thr) {
          const int pos = atomicAdd(&s_cnt[w], 1);
          if (pos < 64) s_list[w][pos] = lane * 4 + it * 256 + e;
        }
      }
    }
    const int nc = min(s_cnt[w], 64);
    float bestv = -FLT_MAX;
    int bestj = 0x7fffffff;
    for (int ci = 0; ci < nc; ++ci) {
      const int j = s_list[w][ci];
      const float4 kv4 = *(const float4*)&kf[(size_t)j * CIN + lane * 4];
      float d = qv.x * kv4.x + qv.y * kv4.y + qv.z * kv4.z + qv.w * kv4.w;
#pragma unroll
      for (int m = 1; m < 64; m <<= 1) d += __shfl_xor(d, m, 64);
      const float val = d * 0.0625f;
      if (val > bestv || (val == bestv && j < bestj)) { bestv = val; bestj = j; }
    }
    if (lane == 0) s_rowidx[rloc] = bestj;
  }
  __syncthreads();

  // ---- phase C: gather v[idx], write quantized + idx ----
  const int n = p0 >> 10, hw0 = p0 & 1023;
  float res[16];
#pragma unroll
  for (int r2 = 0; r2 < 16; ++r2)
    res[r2] = vout[(size_t)s_rowidx[r2] * CIN + t];
  float* ob = outq + (size_t)n * (CIN * 1024) + (size_t)t * 1024 + hw0;
#pragma unroll
  for (int i4 = 0; i4 < 4; ++i4)
    *(float4*)&ob[i4 * 4] = make_float4(res[i4 * 4 + 0], res[i4 * 4 + 1],
                                        res[i4 * 4 + 2], res[i4 * 4 + 3]);
  if (t < 16) outidx[p0 + t] = (float)(s_rowidx[t] & 255);
}

// ---------------------------------------------------------------------------
extern "C" void kernel_launch(void* const* d_in, const int* in_sizes, int n_in,
                              void* d_out, int out_size, void* d_ws,
                              size_t ws_size, hipStream_t stream) {
  const float* latent = (const float*)d_in[0];
  // d_in[1] = temperature (unused in deterministic path)
  const float* codebook = (const float*)d_in[2];
  const float* wq = (const float*)d_in[3];
  const float* wk = (const float*)d_in[4];
  const float* wv = (const float*)d_in[5];

  float* out = (float*)d_out;
  float* outq = out + OFF_QUANT;
  float* outidx = out + OFF_IDX;
  float* outlogit = out + OFF_LOGIT;
  float* outv = out + OFF_V;

  char* ws = (char*)d_ws;
  unsigned short* qb = (unsigned short*)(ws + 0);        // 8 MB
  unsigned short* kb = (unsigned short*)(ws + 8388608);  // 2 MB
  float* kf = (float*)(ws + 10485760);                   // 4 MB
  float* pm1 = (float*)(ws + 14680064);                  // 2 MB
  int* pi1 = (int*)(ws + 16777216);                      // 2 MB
  float* pm2 = (float*)(ws + 18874368);                  // 2 MB
  float* qf = (float*)(ws + 20971520);                   // 16 MB (fp32 q)

  kvq_kernel<<<256 + NPOS / 16, 256, 0, stream>>>(codebook, wk, wv, latent, wq,
                                                  kb, kf, outv, qb, qf);
  logit_kernel<<<4096, 256, 0, stream>>>(qb, kb, outlogit, pm1, pi1, pm2);
  finish_kernel<<<NPOS / 16, 256, 0, stream>>>(pm1, pi1, pm2, outlogit, qf, kf,
                                               outv, outq, outidx);
}